// Round 1
// baseline (106.056 us; speedup 1.0000x reference)
//
#include <hip/hip_runtime.h>
#include <hip/hip_bf16.h>

namespace {

constexpr int GRIDC = 16;                    // 16^3 cells, cell = 0.0625 > max radius 0.06
constexpr int NCELL = GRIDC * GRIDC * GRIDC; // 4096
constexpr int CAP   = 64;                    // per-cell list capacity (avg load ~4)

__device__ __forceinline__ float sigmoid_(float v) {
    if (v >= 0.0f) { float e = expf(-v); return 1.0f / (1.0f + e); }
    float e = expf(v); return e / (1.0f + e);
}

// ---- detect layout of the bool valid_grid buffer --------------------------
// mode 0: uint8 (raw numpy bool), 1: int32, 2: float32
__global__ void VEG_detect(const unsigned char* vg, int* mode) {
    __shared__ int f1, f3;
    if (threadIdx.x == 0) { f1 = 0; f3 = 0; }
    __syncthreads();
    for (int i = threadIdx.x; i < 4096; i += blockDim.x) {
        unsigned char b = vg[i];
        if (b) {
            int m = i & 3;
            if (m == 1) atomicOr(&f1, 1);   // only uint8 layout has data at byte%4==1
            if (m == 3) atomicOr(&f3, 1);   // float32 (0x3F) or uint8 set this
        }
    }
    __syncthreads();
    if (threadIdx.x == 0) {
        int m = f1 ? 0 : (f3 ? 2 : 1);
        *mode = m;
    }
}

// ---- per-gaussian preprocess + grid insertion -----------------------------
__global__ void __launch_bounds__(256)
VEG_prep(const float* __restrict__ xyz, const float* __restrict__ sraw,
         const float* __restrict__ rraw, const float* __restrict__ wraw,
         const float* __restrict__ vraw,
         float* __restrict__ gdata, int* __restrict__ counts,
         int* __restrict__ lists, int ng) {
    int g = blockIdx.x * blockDim.x + threadIdx.x;
    if (g >= ng) return;

    // s = exp(raw), soft-clamped norm (match reference ops exactly)
    float s0 = expf(sraw[g * 3 + 0]);
    float s1 = expf(sraw[g * 3 + 1]);
    float s2 = expf(sraw[g * 3 + 2]);
    float r  = sqrtf(s0 * s0 + s1 * s1 + s2 * s2) + 1e-8f;
    float rs = 0.02f * tanhf(r / 0.02f);
    float fsc = rs / r;
    s0 *= fsc; s1 *= fsc; s2 *= fsc;

    // normalized quaternion -> rotation
    float q0 = rraw[g * 4 + 0], q1 = rraw[g * 4 + 1];
    float q2 = rraw[g * 4 + 2], q3 = rraw[g * 4 + 3];
    float qn = fmaxf(sqrtf(q0 * q0 + q1 * q1 + q2 * q2 + q3 * q3), 1e-12f);
    float inv = 1.0f / qn;
    float rr = q0 * inv, qx = q1 * inv, qy = q2 * inv, qz = q3 * inv;
    float R00 = 1.0f - 2.0f * (qy * qy + qz * qz);
    float R01 = 2.0f * (qx * qy - rr * qz);
    float R02 = 2.0f * (qx * qz + rr * qy);
    float R10 = 2.0f * (qx * qy + rr * qz);
    float R11 = 1.0f - 2.0f * (qx * qx + qz * qz);
    float R12 = 2.0f * (qy * qz - rr * qx);
    float R20 = 2.0f * (qx * qz - rr * qy);
    float R21 = 2.0f * (qy * qz + rr * qx);
    float R22 = 1.0f - 2.0f * (qx * qx + qy * qy);

    float i0 = 1.0f / (s0 * s0), i1 = 1.0f / (s1 * s1), i2 = 1.0f / (s2 * s2);
    float a00 = R00 * R00 * i0 + R01 * R01 * i1 + R02 * R02 * i2;
    float a11 = R10 * R10 * i0 + R11 * R11 * i1 + R12 * R12 * i2;
    float a22 = R20 * R20 * i0 + R21 * R21 * i1 + R22 * R22 * i2;
    float a01 = R00 * R10 * i0 + R01 * R11 * i1 + R02 * R12 * i2;
    float a02 = R00 * R20 * i0 + R01 * R21 * i1 + R02 * R22 * i2;
    float a12 = R10 * R20 * i0 + R11 * R21 * i1 + R12 * R22 * i2;

    float w  = sigmoid_(wraw[g]);
    float v  = sigmoid_(vraw[g]);
    float wv = w * v;

    float cx = xyz[g * 3 + 0], cy = xyz[g * 3 + 1], cz = xyz[g * 3 + 2];
    // qd <= 9  =>  |d| <= 3*max(s_i); margin for fp rounding
    float rad = 3.0f * fmaxf(fmaxf(s0, s1), s2);
    rad = rad * 1.001f + 1e-6f;

    float* o = gdata + (size_t)g * 12;
    o[0] = cx;  o[1] = cy;  o[2] = cz;  o[3] = a00;
    o[4] = a11; o[5] = a22; o[6] = a01; o[7] = a02;
    o[8] = a12; o[9] = w;   o[10] = wv; o[11] = rad;

    // insert into every cell overlapped by the bounding ball's AABB
    int xlo = max(0, (int)floorf((cx - rad) * (float)GRIDC));
    int xhi = min(GRIDC - 1, (int)floorf((cx + rad) * (float)GRIDC));
    int ylo = max(0, (int)floorf((cy - rad) * (float)GRIDC));
    int yhi = min(GRIDC - 1, (int)floorf((cy + rad) * (float)GRIDC));
    int zlo = max(0, (int)floorf((cz - rad) * (float)GRIDC));
    int zhi = min(GRIDC - 1, (int)floorf((cz + rad) * (float)GRIDC));
    for (int zz = zlo; zz <= zhi; ++zz)
        for (int yy = ylo; yy <= yhi; ++yy)
            for (int xx = xlo; xx <= xhi; ++xx) {
                int cell = (zz * GRIDC + yy) * GRIDC + xx;
                int slot = atomicAdd(&counts[cell], 1);
                if (slot < CAP) lists[cell * CAP + slot] = g;
            }
}

// ---- main: one thread per point -------------------------------------------
__global__ void __launch_bounds__(256)
VEG_splat(const float* __restrict__ x, const float* __restrict__ gdata,
          const int* __restrict__ counts, const int* __restrict__ lists,
          const void* __restrict__ valid, const int* __restrict__ mode_p,
          float* __restrict__ out, int npts) {
    int i = blockIdx.x * blockDim.x + threadIdx.x;
    if (i >= npts) return;

    float px = (x[i * 3 + 0] + 1.0f) * 0.5f;
    float py = (x[i * 3 + 1] + 1.0f) * 0.5f;
    float pz = (x[i * 3 + 2] + 1.0f) * 0.5f;

    int ix = min(99, max(0, (int)rintf(px * 99.0f)));   // rintf = round half-to-even
    int iy = min(99, max(0, (int)rintf(py * 99.0f)));
    int iz = min(99, max(0, (int)rintf(pz * 99.0f)));
    int flat = iz * 10000 + iy * 100 + ix;

    int mode = *mode_p;
    bool vb;
    if (mode == 0)      vb = ((const unsigned char*)valid)[flat] != 0;
    else if (mode == 1) vb = ((const int*)valid)[flat] != 0;
    else                vb = ((const float*)valid)[flat] != 0.0f;

    int cx = min(GRIDC - 1, (int)(px * (float)GRIDC));
    int cy = min(GRIDC - 1, (int)(py * (float)GRIDC));
    int cz = min(GRIDC - 1, (int)(pz * (float)GRIDC));
    int cell = (cz * GRIDC + cy) * GRIDC + cx;

    int cnt = min(counts[cell], CAP);
    const int* lst = lists + cell * CAP;

    float den = 0.0f, num = 0.0f;
    for (int j = 0; j < cnt; ++j) {
        int g = lst[j];
        const float4* gd = (const float4*)(gdata + (size_t)g * 12);
        float4 A = gd[0], B = gd[1], C = gd[2];
        float dx = px - A.x, dy = py - A.y, dz = pz - A.z;
        float qd = A.w * dx * dx + B.x * dy * dy + B.y * dz * dz +
                   2.0f * (B.z * dx * dy + B.w * dx * dz + C.x * dy * dz);
        if (qd <= 9.0f) {
            float e = expf(-0.5f * qd);
            den = fmaf(C.y, e, den);
            num = fmaf(C.z, e, num);
        }
    }
    float y = (den > 0.0f) ? (num / den) : -1.0f;
    out[i] = vb ? y : 0.0f;
}

// ---- fallback: brute force with per-block shared staging (if ws too small)
__global__ void __launch_bounds__(256)
VEG_brute(const float* __restrict__ x, const float* __restrict__ xyz,
          const float* __restrict__ sraw, const float* __restrict__ rraw,
          const float* __restrict__ wraw, const float* __restrict__ vraw,
          const void* __restrict__ valid, const int* __restrict__ mode_p,
          float* __restrict__ out, int npts, int ng) {
    __shared__ float sh[256 * 12];
    int i = blockIdx.x * blockDim.x + threadIdx.x;
    bool inb = i < npts;
    float px = 0, py = 0, pz = 0; int flat = 0;
    if (inb) {
        px = (x[i * 3 + 0] + 1.0f) * 0.5f;
        py = (x[i * 3 + 1] + 1.0f) * 0.5f;
        pz = (x[i * 3 + 2] + 1.0f) * 0.5f;
        int ix = min(99, max(0, (int)rintf(px * 99.0f)));
        int iy = min(99, max(0, (int)rintf(py * 99.0f)));
        int iz = min(99, max(0, (int)rintf(pz * 99.0f)));
        flat = iz * 10000 + iy * 100 + ix;
    }
    float den = 0.0f, num = 0.0f;
    for (int base = 0; base < ng; base += 256) {
        __syncthreads();
        int g = base + threadIdx.x;
        if (g < ng) {
            float s0 = expf(sraw[g * 3 + 0]);
            float s1 = expf(sraw[g * 3 + 1]);
            float s2 = expf(sraw[g * 3 + 2]);
            float r  = sqrtf(s0 * s0 + s1 * s1 + s2 * s2) + 1e-8f;
            float rs = 0.02f * tanhf(r / 0.02f);
            float fsc = rs / r;
            s0 *= fsc; s1 *= fsc; s2 *= fsc;
            float q0 = rraw[g * 4 + 0], q1 = rraw[g * 4 + 1];
            float q2 = rraw[g * 4 + 2], q3 = rraw[g * 4 + 3];
            float qn = fmaxf(sqrtf(q0 * q0 + q1 * q1 + q2 * q2 + q3 * q3), 1e-12f);
            float inv = 1.0f / qn;
            float rr = q0 * inv, qx = q1 * inv, qy = q2 * inv, qz = q3 * inv;
            float R00 = 1.0f - 2.0f * (qy * qy + qz * qz);
            float R01 = 2.0f * (qx * qy - rr * qz);
            float R02 = 2.0f * (qx * qz + rr * qy);
            float R10 = 2.0f * (qx * qy + rr * qz);
            float R11 = 1.0f - 2.0f * (qx * qx + qz * qz);
            float R12 = 2.0f * (qy * qz - rr * qx);
            float R20 = 2.0f * (qx * qz - rr * qy);
            float R21 = 2.0f * (qy * qz + rr * qx);
            float R22 = 1.0f - 2.0f * (qx * qx + qy * qy);
            float i0 = 1.0f / (s0 * s0), i1 = 1.0f / (s1 * s1), i2 = 1.0f / (s2 * s2);
            float* o = sh + threadIdx.x * 12;
            o[0] = xyz[g * 3 + 0]; o[1] = xyz[g * 3 + 1]; o[2] = xyz[g * 3 + 2];
            o[3] = R00 * R00 * i0 + R01 * R01 * i1 + R02 * R02 * i2;
            o[4] = R10 * R10 * i0 + R11 * R11 * i1 + R12 * R12 * i2;
            o[5] = R20 * R20 * i0 + R21 * R21 * i1 + R22 * R22 * i2;
            o[6] = R00 * R10 * i0 + R01 * R11 * i1 + R02 * R12 * i2;
            o[7] = R00 * R20 * i0 + R01 * R21 * i1 + R02 * R22 * i2;
            o[8] = R10 * R20 * i0 + R11 * R21 * i1 + R12 * R22 * i2;
            float w = sigmoid_(wraw[g]);
            float v = sigmoid_(vraw[g]);
            o[9] = w; o[10] = w * v; o[11] = 0.0f;
        }
        __syncthreads();
        int tile = min(256, ng - base);
        if (inb) {
            for (int j = 0; j < tile; ++j) {
                const float* o = sh + j * 12;
                float dx = px - o[0], dy = py - o[1], dz = pz - o[2];
                float qd = o[3] * dx * dx + o[4] * dy * dy + o[5] * dz * dz +
                           2.0f * (o[6] * dx * dy + o[7] * dx * dz + o[8] * dy * dz);
                if (qd <= 9.0f) {
                    float e = expf(-0.5f * qd);
                    den = fmaf(o[9], e, den);
                    num = fmaf(o[10], e, num);
                }
            }
        }
    }
    if (inb) {
        int mode = *mode_p;
        bool vb;
        if (mode == 0)      vb = ((const unsigned char*)valid)[flat] != 0;
        else if (mode == 1) vb = ((const int*)valid)[flat] != 0;
        else                vb = ((const float*)valid)[flat] != 0.0f;
        float y = (den > 0.0f) ? (num / den) : -1.0f;
        out[i] = vb ? y : 0.0f;
    }
}

} // namespace

extern "C" void kernel_launch(void* const* d_in, const int* in_sizes, int n_in,
                              void* d_out, int out_size, void* d_ws, size_t ws_size,
                              hipStream_t stream) {
    const float* x    = (const float*)d_in[0];
    const float* xyz  = (const float*)d_in[1];
    const float* sraw = (const float*)d_in[2];
    const float* rraw = (const float*)d_in[3];
    const float* wraw = (const float*)d_in[4];
    const float* vraw = (const float*)d_in[5];
    const void*  valid = d_in[6];
    float* out = (float*)d_out;

    int npts = in_sizes[0] / 3;
    int ng   = in_sizes[4];

    char* ws = (char*)d_ws;
    size_t mode_off   = 0;
    size_t gdata_off  = 256;
    size_t counts_off = gdata_off + (size_t)ng * 12 * sizeof(float);
    counts_off = (counts_off + 255) & ~(size_t)255;
    size_t lists_off  = counts_off + (size_t)NCELL * sizeof(int);
    size_t total      = lists_off + (size_t)NCELL * CAP * sizeof(int);

    int* mode = (int*)(ws + mode_off);

    VEG_detect<<<1, 256, 0, stream>>>((const unsigned char*)valid, mode);

    if (ws_size >= total) {
        float* gdata = (float*)(ws + gdata_off);
        int* counts  = (int*)(ws + counts_off);
        int* lists   = (int*)(ws + lists_off);
        hipMemsetAsync(counts, 0, (size_t)NCELL * sizeof(int), stream);
        VEG_prep<<<(ng + 255) / 256, 256, 0, stream>>>(xyz, sraw, rraw, wraw, vraw,
                                                       gdata, counts, lists, ng);
        VEG_splat<<<(npts + 255) / 256, 256, 0, stream>>>(x, gdata, counts, lists,
                                                          valid, mode, out, npts);
    } else {
        VEG_brute<<<(npts + 255) / 256, 256, 0, stream>>>(x, xyz, sraw, rraw, wraw,
                                                          vraw, valid, mode, out,
                                                          npts, ng);
    }
}

// Round 2
// 104.757 us; speedup vs baseline: 1.0124x; 1.0124x over previous
//
#include <hip/hip_runtime.h>
#include <hip/hip_bf16.h>

namespace {

constexpr int GRIDC = 16;                    // 16^3 cells, cell = 0.0625 > max radius 0.06
constexpr int NCELL = GRIDC * GRIDC * GRIDC; // 4096
constexpr int CAP   = 48;                    // per-cell list capacity (avg load ~4)

__device__ __forceinline__ float sigmoid_(float v) {
    if (v >= 0.0f) { float e = expf(-v); return 1.0f / (1.0f + e); }
    float e = expf(v); return e / (1.0f + e);
}

// ---- fused: valid_grid layout detect + zero counts + per-gaussian preprocess
//      + grid insertion, all in ONE block (LDS cell counters, no global memset)
__global__ void __launch_bounds__(1024)
VEG_setup(const unsigned char* __restrict__ vg,
          const float* __restrict__ xyz, const float* __restrict__ sraw,
          const float* __restrict__ rraw, const float* __restrict__ wraw,
          const float* __restrict__ vraw,
          float* __restrict__ gdata, int* __restrict__ counts,
          int* __restrict__ lists, int* __restrict__ mode_p, int ng) {
    __shared__ int scount[NCELL];
    __shared__ int f1, f3;
    if (threadIdx.x == 0) { f1 = 0; f3 = 0; }
    for (int c = threadIdx.x; c < NCELL; c += 1024) scount[c] = 0;
    __syncthreads();

    // --- detect layout of the bool valid_grid buffer (scan first 4096 bytes)
    // mode 0: uint8 (numpy bool), 1: int32, 2: float32
    int l1 = 0, l3 = 0;
    for (int i = threadIdx.x; i < 4096; i += 1024) {
        unsigned char b = vg[i];
        if (b) {
            int m = i & 3;
            if (m == 1) l1 = 1;   // only uint8 layout has data at byte%4==1
            if (m == 3) l3 = 1;   // float32 (0x3F) or uint8 set this
        }
    }
    if (l1) atomicOr(&f1, 1);
    if (l3) atomicOr(&f3, 1);

    // --- per-gaussian preprocess + insert
    for (int g = threadIdx.x; g < ng; g += 1024) {
        float s0 = expf(sraw[g * 3 + 0]);
        float s1 = expf(sraw[g * 3 + 1]);
        float s2 = expf(sraw[g * 3 + 2]);
        float r  = sqrtf(s0 * s0 + s1 * s1 + s2 * s2) + 1e-8f;
        float rs = 0.02f * tanhf(r / 0.02f);
        float fsc = rs / r;
        s0 *= fsc; s1 *= fsc; s2 *= fsc;

        float q0 = rraw[g * 4 + 0], q1 = rraw[g * 4 + 1];
        float q2 = rraw[g * 4 + 2], q3 = rraw[g * 4 + 3];
        float qn = fmaxf(sqrtf(q0 * q0 + q1 * q1 + q2 * q2 + q3 * q3), 1e-12f);
        float inv = 1.0f / qn;
        float rr = q0 * inv, qx = q1 * inv, qy = q2 * inv, qz = q3 * inv;
        float R00 = 1.0f - 2.0f * (qy * qy + qz * qz);
        float R01 = 2.0f * (qx * qy - rr * qz);
        float R02 = 2.0f * (qx * qz + rr * qy);
        float R10 = 2.0f * (qx * qy + rr * qz);
        float R11 = 1.0f - 2.0f * (qx * qx + qz * qz);
        float R12 = 2.0f * (qy * qz - rr * qx);
        float R20 = 2.0f * (qx * qz - rr * qy);
        float R21 = 2.0f * (qy * qz + rr * qx);
        float R22 = 1.0f - 2.0f * (qx * qx + qy * qy);

        float i0 = 1.0f / (s0 * s0), i1 = 1.0f / (s1 * s1), i2 = 1.0f / (s2 * s2);
        float a00 = R00 * R00 * i0 + R01 * R01 * i1 + R02 * R02 * i2;
        float a11 = R10 * R10 * i0 + R11 * R11 * i1 + R12 * R12 * i2;
        float a22 = R20 * R20 * i0 + R21 * R21 * i1 + R22 * R22 * i2;
        float a01 = R00 * R10 * i0 + R01 * R11 * i1 + R02 * R12 * i2;
        float a02 = R00 * R20 * i0 + R01 * R21 * i1 + R02 * R22 * i2;
        float a12 = R10 * R20 * i0 + R11 * R21 * i1 + R12 * R22 * i2;

        float w  = sigmoid_(wraw[g]);
        float v  = sigmoid_(vraw[g]);

        float cx = xyz[g * 3 + 0], cy = xyz[g * 3 + 1], cz = xyz[g * 3 + 2];
        float rad = 3.0f * fmaxf(fmaxf(s0, s1), s2);   // qd<=9 => |d|<=3*max(s)
        rad = rad * 1.001f + 1e-6f;

        float* o = gdata + (size_t)g * 12;
        o[0] = cx;  o[1] = cy;  o[2] = cz;  o[3] = a00;
        o[4] = a11; o[5] = a22; o[6] = a01; o[7] = a02;
        o[8] = a12; o[9] = w;   o[10] = w * v; o[11] = rad;

        int xlo = max(0, (int)floorf((cx - rad) * (float)GRIDC));
        int xhi = min(GRIDC - 1, (int)floorf((cx + rad) * (float)GRIDC));
        int ylo = max(0, (int)floorf((cy - rad) * (float)GRIDC));
        int yhi = min(GRIDC - 1, (int)floorf((cy + rad) * (float)GRIDC));
        int zlo = max(0, (int)floorf((cz - rad) * (float)GRIDC));
        int zhi = min(GRIDC - 1, (int)floorf((cz + rad) * (float)GRIDC));
        for (int zz = zlo; zz <= zhi; ++zz)
            for (int yy = ylo; yy <= yhi; ++yy)
                for (int xx = xlo; xx <= xhi; ++xx) {
                    int cell = (zz * GRIDC + yy) * GRIDC + xx;
                    int slot = atomicAdd(&scount[cell], 1);
                    if (slot < CAP) lists[cell * CAP + slot] = g;
                }
    }
    __syncthreads();
    for (int c = threadIdx.x; c < NCELL; c += 1024) counts[c] = scount[c];
    if (threadIdx.x == 0) *mode_p = f1 ? 0 : (f3 ? 2 : 1);
}

// ---- main: one thread per point, x staged through LDS (coalesced float4) --
__global__ void __launch_bounds__(256)
VEG_splat(const float* __restrict__ x, const float* __restrict__ gdata,
          const int* __restrict__ counts, const int* __restrict__ lists,
          const void* __restrict__ valid, const int* __restrict__ mode_p,
          float* __restrict__ out, int npts) {
    __shared__ float shx[768];
    int base = blockIdx.x * 256;
    int nrem = npts - base;
    if (nrem >= 256) {
        if (threadIdx.x < 192)
            ((float4*)shx)[threadIdx.x] = ((const float4*)(x + (size_t)base * 3))[threadIdx.x];
    } else {
        for (int j = threadIdx.x; j < nrem * 3; j += 256)
            shx[j] = x[(size_t)base * 3 + j];
    }
    __syncthreads();

    int i = base + threadIdx.x;
    if (i >= npts) return;

    float px = (shx[threadIdx.x * 3 + 0] + 1.0f) * 0.5f;
    float py = (shx[threadIdx.x * 3 + 1] + 1.0f) * 0.5f;
    float pz = (shx[threadIdx.x * 3 + 2] + 1.0f) * 0.5f;

    int ix = min(99, max(0, (int)rintf(px * 99.0f)));   // rintf = round half-to-even
    int iy = min(99, max(0, (int)rintf(py * 99.0f)));
    int iz = min(99, max(0, (int)rintf(pz * 99.0f)));
    int flat = iz * 10000 + iy * 100 + ix;

    int mode = *mode_p;
    bool vb;
    if (mode == 0)      vb = ((const unsigned char*)valid)[flat] != 0;
    else if (mode == 1) vb = ((const int*)valid)[flat] != 0;
    else                vb = ((const float*)valid)[flat] != 0.0f;

    int cx = min(GRIDC - 1, (int)(px * (float)GRIDC));
    int cy = min(GRIDC - 1, (int)(py * (float)GRIDC));
    int cz = min(GRIDC - 1, (int)(pz * (float)GRIDC));
    int cell = (cz * GRIDC + cy) * GRIDC + cx;

    int cnt = min(counts[cell], CAP);
    const int* lst = lists + cell * CAP;

    float den = 0.0f, num = 0.0f;
    for (int j = 0; j < cnt; ++j) {
        int g = lst[j];
        const float4* gd = (const float4*)(gdata + (size_t)g * 12);
        float4 A = gd[0], B = gd[1], C = gd[2];
        float dx = px - A.x, dy = py - A.y, dz = pz - A.z;
        float qd = A.w * dx * dx + B.x * dy * dy + B.y * dz * dz +
                   2.0f * (B.z * dx * dy + B.w * dx * dz + C.x * dy * dz);
        if (qd <= 9.0f) {
            float e = expf(-0.5f * qd);
            den = fmaf(C.y, e, den);
            num = fmaf(C.z, e, num);
        }
    }
    float y = (den > 0.0f) ? (num / den) : -1.0f;
    out[i] = vb ? y : 0.0f;
}

// ---- fallback: brute force (only if ws_size is absurdly small) ------------
__global__ void VEG_detect(const unsigned char* vg, int* mode) {
    __shared__ int f1, f3;
    if (threadIdx.x == 0) { f1 = 0; f3 = 0; }
    __syncthreads();
    for (int i = threadIdx.x; i < 4096; i += blockDim.x) {
        unsigned char b = vg[i];
        if (b) {
            int m = i & 3;
            if (m == 1) atomicOr(&f1, 1);
            if (m == 3) atomicOr(&f3, 1);
        }
    }
    __syncthreads();
    if (threadIdx.x == 0) *mode = f1 ? 0 : (f3 ? 2 : 1);
}

__global__ void __launch_bounds__(256)
VEG_brute(const float* __restrict__ x, const float* __restrict__ xyz,
          const float* __restrict__ sraw, const float* __restrict__ rraw,
          const float* __restrict__ wraw, const float* __restrict__ vraw,
          const void* __restrict__ valid, const int* __restrict__ mode_p,
          float* __restrict__ out, int npts, int ng) {
    __shared__ float sh[256 * 12];
    int i = blockIdx.x * blockDim.x + threadIdx.x;
    bool inb = i < npts;
    float px = 0, py = 0, pz = 0; int flat = 0;
    if (inb) {
        px = (x[i * 3 + 0] + 1.0f) * 0.5f;
        py = (x[i * 3 + 1] + 1.0f) * 0.5f;
        pz = (x[i * 3 + 2] + 1.0f) * 0.5f;
        int ix = min(99, max(0, (int)rintf(px * 99.0f)));
        int iy = min(99, max(0, (int)rintf(py * 99.0f)));
        int iz = min(99, max(0, (int)rintf(pz * 99.0f)));
        flat = iz * 10000 + iy * 100 + ix;
    }
    float den = 0.0f, num = 0.0f;
    for (int base = 0; base < ng; base += 256) {
        __syncthreads();
        int g = base + threadIdx.x;
        if (g < ng) {
            float s0 = expf(sraw[g * 3 + 0]);
            float s1 = expf(sraw[g * 3 + 1]);
            float s2 = expf(sraw[g * 3 + 2]);
            float r  = sqrtf(s0 * s0 + s1 * s1 + s2 * s2) + 1e-8f;
            float rs = 0.02f * tanhf(r / 0.02f);
            float fsc = rs / r;
            s0 *= fsc; s1 *= fsc; s2 *= fsc;
            float q0 = rraw[g * 4 + 0], q1 = rraw[g * 4 + 1];
            float q2 = rraw[g * 4 + 2], q3 = rraw[g * 4 + 3];
            float qn = fmaxf(sqrtf(q0 * q0 + q1 * q1 + q2 * q2 + q3 * q3), 1e-12f);
            float inv = 1.0f / qn;
            float rr = q0 * inv, qx = q1 * inv, qy = q2 * inv, qz = q3 * inv;
            float R00 = 1.0f - 2.0f * (qy * qy + qz * qz);
            float R01 = 2.0f * (qx * qy - rr * qz);
            float R02 = 2.0f * (qx * qz + rr * qy);
            float R10 = 2.0f * (qx * qy + rr * qz);
            float R11 = 1.0f - 2.0f * (qx * qx + qz * qz);
            float R12 = 2.0f * (qy * qz - rr * qx);
            float R20 = 2.0f * (qx * qz - rr * qy);
            float R21 = 2.0f * (qy * qz + rr * qx);
            float R22 = 1.0f - 2.0f * (qx * qx + qy * qy);
            float i0 = 1.0f / (s0 * s0), i1 = 1.0f / (s1 * s1), i2 = 1.0f / (s2 * s2);
            float* o = sh + threadIdx.x * 12;
            o[0] = xyz[g * 3 + 0]; o[1] = xyz[g * 3 + 1]; o[2] = xyz[g * 3 + 2];
            o[3] = R00 * R00 * i0 + R01 * R01 * i1 + R02 * R02 * i2;
            o[4] = R10 * R10 * i0 + R11 * R11 * i1 + R12 * R12 * i2;
            o[5] = R20 * R20 * i0 + R21 * R21 * i1 + R22 * R22 * i2;
            o[6] = R00 * R10 * i0 + R01 * R11 * i1 + R02 * R12 * i2;
            o[7] = R00 * R20 * i0 + R01 * R21 * i1 + R02 * R22 * i2;
            o[8] = R10 * R20 * i0 + R11 * R21 * i1 + R12 * R22 * i2;
            float w = sigmoid_(wraw[g]);
            float v = sigmoid_(vraw[g]);
            o[9] = w; o[10] = w * v; o[11] = 0.0f;
        }
        __syncthreads();
        int tile = min(256, ng - base);
        if (inb) {
            for (int j = 0; j < tile; ++j) {
                const float* o = sh + j * 12;
                float dx = px - o[0], dy = py - o[1], dz = pz - o[2];
                float qd = o[3] * dx * dx + o[4] * dy * dy + o[5] * dz * dz +
                           2.0f * (o[6] * dx * dy + o[7] * dx * dz + o[8] * dy * dz);
                if (qd <= 9.0f) {
                    float e = expf(-0.5f * qd);
                    den = fmaf(o[9], e, den);
                    num = fmaf(o[10], e, num);
                }
            }
        }
    }
    if (inb) {
        int mode = *mode_p;
        bool vb;
        if (mode == 0)      vb = ((const unsigned char*)valid)[flat] != 0;
        else if (mode == 1) vb = ((const int*)valid)[flat] != 0;
        else                vb = ((const float*)valid)[flat] != 0.0f;
        float y = (den > 0.0f) ? (num / den) : -1.0f;
        out[i] = vb ? y : 0.0f;
    }
}

} // namespace

extern "C" void kernel_launch(void* const* d_in, const int* in_sizes, int n_in,
                              void* d_out, int out_size, void* d_ws, size_t ws_size,
                              hipStream_t stream) {
    const float* x    = (const float*)d_in[0];
    const float* xyz  = (const float*)d_in[1];
    const float* sraw = (const float*)d_in[2];
    const float* rraw = (const float*)d_in[3];
    const float* wraw = (const float*)d_in[4];
    const float* vraw = (const float*)d_in[5];
    const void*  valid = d_in[6];
    float* out = (float*)d_out;

    int npts = in_sizes[0] / 3;
    int ng   = in_sizes[4];

    char* ws = (char*)d_ws;
    size_t mode_off   = 0;
    size_t gdata_off  = 256;
    size_t counts_off = gdata_off + (size_t)ng * 12 * sizeof(float);
    counts_off = (counts_off + 255) & ~(size_t)255;
    size_t lists_off  = counts_off + (size_t)NCELL * sizeof(int);
    size_t total      = lists_off + (size_t)NCELL * CAP * sizeof(int);

    int* mode = (int*)(ws + mode_off);

    if (ws_size >= total) {
        float* gdata = (float*)(ws + gdata_off);
        int* counts  = (int*)(ws + counts_off);
        int* lists   = (int*)(ws + lists_off);
        VEG_setup<<<1, 1024, 0, stream>>>((const unsigned char*)valid, xyz, sraw,
                                          rraw, wraw, vraw, gdata, counts, lists,
                                          mode, ng);
        VEG_splat<<<(npts + 255) / 256, 256, 0, stream>>>(x, gdata, counts, lists,
                                                          valid, mode, out, npts);
    } else {
        VEG_detect<<<1, 256, 0, stream>>>((const unsigned char*)valid, mode);
        VEG_brute<<<(npts + 255) / 256, 256, 0, stream>>>(x, xyz, sraw, rraw, wraw,
                                                          vraw, valid, mode, out,
                                                          npts, ng);
    }
}